// Round 2
// baseline (66688.062 us; speedup 1.0000x reference)
//
#include <hip/hip_runtime.h>
#include <cmath>

// ---------------- problem constants ----------------
#define BATCH 64
#define SEQL  512
#define INDIM 512
#define HID   768
#define G4    3072          // 4*HID
#define KTOT  1280          // INDIM + HID
#define KS    10            // K splits (chunk = 128)
#define KC    128
#define JB    24            // row blocks of 128 rows
#define RPB   128
#define NBLK  480           // 2 * JB * KS ; 64KB weight tile each = 31.46MB total
#define NTHR  256
#define E2    (2*BATCH*HID)
#define HALLN ((size_t)BATCH*SEQL*2*HID)

// ---------------- device-scope grid barrier ----------------
__device__ __forceinline__ void grid_barrier(unsigned* cnt, unsigned target) {
    __syncthreads();
    if (threadIdx.x == 0) {
        __threadfence();
        __hip_atomic_fetch_add(cnt, 1u, __ATOMIC_RELAXED, __HIP_MEMORY_SCOPE_AGENT);
        while (__hip_atomic_load(cnt, __ATOMIC_RELAXED, __HIP_MEMORY_SCOPE_AGENT) < target)
            __builtin_amdgcn_s_sleep(1);
        __threadfence();
    }
    __syncthreads();
}

__device__ __forceinline__ float sigmoidf_(float x) { return 1.0f / (1.0f + expf(-x)); }

// ---------------- pre-kernel: transpose x -> xT[t][k][b] ----------------
__global__ __launch_bounds__(256) void k_transpose_x(const float* __restrict__ x,
                                                     float* __restrict__ xT) {
    __shared__ float tile[64][65];
    const int t  = blockIdx.x >> 3;
    const int kt = (blockIdx.x & 7) * 64;
    const int tid = threadIdx.x;
#pragma unroll
    for (int p = 0; p < 16; ++p) {
        int idx = p * 256 + tid;
        int b = idx >> 6, kl = idx & 63;
        tile[b][kl] = x[((size_t)b * SEQL + t) * INDIM + kt + kl];
    }
    __syncthreads();
#pragma unroll
    for (int p = 0; p < 16; ++p) {
        int idx = p * 256 + tid;
        int kl = idx >> 6, b = idx & 63;
        xT[((size_t)t * INDIM + kt + kl) * BATCH + b] = tile[b][kl];
    }
}

// ---------------- pre-kernel: pack weights -> Wt[d][k][r] ----------------
__global__ __launch_bounds__(256) void k_pack_w(const float* __restrict__ wih0,
                                                const float* __restrict__ whh0,
                                                const float* __restrict__ wih1,
                                                const float* __restrict__ whh1,
                                                float* __restrict__ Wt) {
    __shared__ float tile[64][65];
    const int d   = blockIdx.x / 960;
    const int rem = blockIdx.x % 960;
    const int kt  = rem / 48;
    const int rt  = rem % 48;
    const float* wih = d ? wih1 : wih0;
    const float* whh = d ? whh1 : whh0;
    const int kbase = kt * 64, rbase = rt * 64;
    const int tid = threadIdx.x;
#pragma unroll
    for (int p = 0; p < 16; ++p) {
        int idx = p * 256 + tid;
        int rl = idx >> 6, kl = idx & 63;
        int k = kbase + kl, r = rbase + rl;
        tile[rl][kl] = (k < INDIM) ? wih[(size_t)r * INDIM + k]
                                   : whh[(size_t)r * HID + (k - INDIM)];
    }
    __syncthreads();
#pragma unroll
    for (int p = 0; p < 16; ++p) {
        int idx = p * 256 + tid;
        int kl = idx >> 6, rl = idx & 63;
        Wt[((size_t)d * KTOT + kbase + kl) * G4 + rbase + rl] = tile[rl][kl];
    }
}

// ---------------- persistent LSTM: weights pinned in LDS ----------------
// INL=1: input tile staged in LDS (needs 80KB dyn LDS). INL=0: 64KB, inputs via L1 broadcast.
template <int INL>
__global__ __launch_bounds__(NTHR, 2)
void k_lstm_persist(const float* __restrict__ x,   const float* __restrict__ xT, int use_xt,
                    const float* __restrict__ Wt,  int use_wt,
                    const float* __restrict__ wih0, const float* __restrict__ whh0,
                    const float* __restrict__ wih1, const float* __restrict__ whh1,
                    const float* __restrict__ bias0, const float* __restrict__ bias1,
                    const float* __restrict__ h0,   const float* __restrict__ c0,
                    float* __restrict__ out,  float* __restrict__ Gpart,
                    float* __restrict__ hT,   float* __restrict__ cbuf,
                    unsigned* __restrict__ barcnt)
{
    extern __shared__ float smem[];
    float* WL  = smem;                 // [KC][RPB]  128*128 floats = 64KB
    float* InL = smem + KC * RPB;      // [64][BATCH] 64*64 floats = 16KB (INL=1)

    const int tid = threadIdx.x;
    const int bid = blockIdx.x;
    const int d   = bid / (JB * KS);
    const int rem = bid % (JB * KS);
    const int rb  = rem / KS;
    const int kb  = rem % KS;
    const int r0  = rb * RPB;
    const int k0  = kb * KC;
    const int tr  = tid & 31;          // 32 r-threads * 4 cols (b128)
    const int tb  = tid >> 5;          // 8 b-threads * 8 rows
    const int gtid = bid * NTHR + tid;
    unsigned bar = 0;

    // ---- load this block's 128x128 weight tile into LDS (once) ----
    if (use_wt) {
        const float* wbase = Wt + (size_t)d * KTOT * G4;
#pragma unroll
        for (int p = 0; p < 16; ++p) {
            int idx = p * NTHR + tid;          // 0..4095 float4 slots
            int f4 = idx & 31, kl = idx >> 5;  // kl 0..127
            *(float4*)&WL[kl * RPB + f4 * 4] =
                *(const float4*)(wbase + (size_t)(k0 + kl) * G4 + r0 + f4 * 4);
        }
    } else {
        const float* wih = d ? wih1 : wih0;
        const float* whh = d ? whh1 : whh0;
        for (int p = 0; p < 64; ++p) {
            int idx = p * NTHR + tid;          // 0..16383
            int r = idx & 127, kl = idx >> 7;
            int k = k0 + kl;
            WL[kl * RPB + r] = (k < INDIM)
                ? wih[(size_t)(r0 + r) * INDIM + k]
                : whh[(size_t)(r0 + r) * HID + (k - INDIM)];
        }
    }

    // ---- init: h0 -> hT (transposed), c0 -> cbuf ----
    for (int e = gtid; e < E2; e += NBLK * NTHR) {
        int b = e / (2 * HID); int rr = e % (2 * HID); int dd = rr / HID; int j = rr % HID;
        size_t src = (size_t)(dd * BATCH + b) * HID + j;
        hT[(size_t)(dd * HID + j) * BATCH + b] = h0[src];
        cbuf[src] = c0[src];
    }
    grid_barrier(barcnt, (++bar) * NBLK);

    for (int t = 0; t < SEQL; ++t) {
        const int t_eff = d ? (SEQL - 1 - t) : t;

        // ================= phase 1: partial GEMM (K chunk in LDS weights) =====
        float acc[8][4];
#pragma unroll
        for (int i = 0; i < 8; ++i)
#pragma unroll
            for (int m = 0; m < 4; ++m) acc[i][m] = 0.0f;

#pragma unroll
        for (int c = 0; c < 2; ++c) {           // two 64-k sub-chunks
            const int kc0 = k0 + c * 64;
            const float* src64 = (kc0 < INDIM)
                ? (use_xt ? xT + ((size_t)t_eff * INDIM + kc0) * BATCH : nullptr)
                : (hT + ((size_t)d * HID + (kc0 - INDIM)) * BATCH);

            if (INL) {
                __syncthreads();                // protect InL reuse
                if (src64) {
#pragma unroll
                    for (int p = 0; p < 4; ++p) {
                        int idx = p * NTHR + tid;        // 1024 float4 slots
                        int b4 = idx & 15, kr = idx >> 4;
                        *(float4*)&InL[kr * BATCH + b4 * 4] =
                            *(const float4*)(src64 + (size_t)kr * BATCH + b4 * 4);
                    }
                } else {                         // x direct (slow fallback)
#pragma unroll
                    for (int p = 0; p < 16; ++p) {
                        int idx = p * NTHR + tid;
                        int b = idx & 63, kr = idx >> 6;
                        InL[kr * BATCH + b] =
                            x[((size_t)b * SEQL + t_eff) * INDIM + kc0 + kr];
                    }
                }
                __syncthreads();
#pragma unroll 8
                for (int k = 0; k < 64; ++k) {
                    float4 w = *(const float4*)&WL[(c * 64 + k) * RPB + tr * 4];
                    float4 a0 = *(const float4*)&InL[k * BATCH + tb * 8];
                    float4 a1 = *(const float4*)&InL[k * BATCH + tb * 8 + 4];
                    float av[8] = {a0.x, a0.y, a0.z, a0.w, a1.x, a1.y, a1.z, a1.w};
                    float wv[4] = {w.x, w.y, w.z, w.w};
#pragma unroll
                    for (int bi = 0; bi < 8; ++bi)
#pragma unroll
                        for (int m = 0; m < 4; ++m)
                            acc[bi][m] = fmaf(av[bi], wv[m], acc[bi][m]);
                }
            } else {
                // inputs straight from global (L1 broadcast; half-wave uniform addr)
#pragma unroll 4
                for (int k = 0; k < 64; ++k) {
                    float4 w = *(const float4*)&WL[(c * 64 + k) * RPB + tr * 4];
                    float av[8];
                    if (src64) {
                        float4 a0 = *(const float4*)(src64 + (size_t)k * BATCH + tb * 8);
                        float4 a1 = *(const float4*)(src64 + (size_t)k * BATCH + tb * 8 + 4);
                        av[0]=a0.x; av[1]=a0.y; av[2]=a0.z; av[3]=a0.w;
                        av[4]=a1.x; av[5]=a1.y; av[6]=a1.z; av[7]=a1.w;
                    } else {
#pragma unroll
                        for (int bi = 0; bi < 8; ++bi)
                            av[bi] = x[((size_t)(tb * 8 + bi) * SEQL + t_eff) * INDIM + kc0 + k];
                    }
                    float wv[4] = {w.x, w.y, w.z, w.w};
#pragma unroll
                    for (int bi = 0; bi < 8; ++bi)
#pragma unroll
                        for (int m = 0; m < 4; ++m)
                            acc[bi][m] = fmaf(av[bi], wv[m], acc[bi][m]);
                }
            }
        }
        // ---- write partials: Gpart[d*KS+kb][b][r0..r0+127] ----
        {
            float* gp = Gpart + (size_t)(d * KS + kb) * ((size_t)BATCH * G4);
#pragma unroll
            for (int bi = 0; bi < 8; ++bi)
                *(float4*)(gp + (size_t)(tb * 8 + bi) * G4 + r0 + tr * 4) =
                    make_float4(acc[bi][0], acc[bi][1], acc[bi][2], acc[bi][3]);
        }
        grid_barrier(barcnt, (++bar) * NBLK);

        // ================= phase 2: reduce + activations + state ==============
        for (int e = gtid; e < E2; e += NBLK * NTHR) {
            int b = e / (2 * HID); int rr = e % (2 * HID); int dd = rr / HID; int j = rr % HID;
            const float* bs = dd ? bias1 : bias0;
            float gv[4];
#pragma unroll
            for (int gi = 0; gi < 4; ++gi) {
                int row = gi * HID + j;
                float s = bs[row];
#pragma unroll
                for (int q = 0; q < KS; ++q)
                    s += Gpart[(size_t)(dd * KS + q) * ((size_t)BATCH * G4) + (size_t)b * G4 + row];
                gv[gi] = s;
            }
            float ig = sigmoidf_(gv[0]);
            float fg = sigmoidf_(gv[1]);
            float gg = tanhf(gv[2]);
            float og = sigmoidf_(gv[3]);
            size_t ci = (size_t)(dd * BATCH + b) * HID + j;
            float cn = fg * cbuf[ci] + ig * gg;
            cbuf[ci] = cn;
            float hn = og * tanhf(cn);
            hT[(size_t)(dd * HID + j) * BATCH + b] = hn;
            int t_out = dd ? (SEQL - 1 - t) : t;
            out[((size_t)b * SEQL + t_out) * (2 * HID) + dd * HID + j] = hn;
            if (t == SEQL - 1) {
                out[HALLN + ci] = hn;
                out[HALLN + E2 + ci] = cn;
            }
        }
        grid_barrier(barcnt, (++bar) * NBLK);
    }
}

// ---------------- launcher ----------------
extern "C" void kernel_launch(void* const* d_in, const int* in_sizes, int n_in,
                              void* d_out, int out_size, void* d_ws, size_t ws_size,
                              hipStream_t stream) {
    const float* x     = (const float*)d_in[0];
    const float* wih0  = (const float*)d_in[1];
    const float* whh0  = (const float*)d_in[2];
    const float* bias0 = (const float*)d_in[3];
    const float* wih1  = (const float*)d_in[4];
    const float* whh1  = (const float*)d_in[5];
    const float* bias1 = (const float*)d_in[6];
    const float* h0    = (const float*)d_in[7];
    const float* c0    = (const float*)d_in[8];
    float* out = (float*)d_out;
    float* ws  = (float*)d_ws;

    size_t off = 0;
    float* Gpart = ws + off; off += (size_t)2 * KS * BATCH * G4;
    float* hT    = ws + off; off += (size_t)2 * HID * BATCH;
    float* cbuf  = ws + off; off += (size_t)2 * BATCH * HID;
    unsigned* barcnt = (unsigned*)(ws + off); off += 64;
    float* Wt = ws + off;
    size_t off_wt = off + (size_t)2 * KTOT * G4;
    float* xT = ws + off_wt;
    size_t off_xt = off_wt + (size_t)SEQL * INDIM * BATCH;
    int use_wt = (ws_size >= off_wt * sizeof(float)) ? 1 : 0;
    int use_xt = (ws_size >= off_xt * sizeof(float)) ? 1 : 0;

    hipMemsetAsync(barcnt, 0, 256, stream);
    if (use_wt) k_pack_w<<<1920, 256, 0, stream>>>(wih0, whh0, wih1, whh1, Wt);
    if (use_xt) k_transpose_x<<<4096, 256, 0, stream>>>(x, xT);

    // 80KB dynamic LDS needs opt-in; fall back to 64KB no-InL variant if refused.
    static int inl_mode = -1;   // decided once; same decision every call (no work change)
    if (inl_mode < 0) {
        hipError_t e = hipFuncSetAttribute(
            reinterpret_cast<const void*>(&k_lstm_persist<1>),
            hipFuncAttributeMaxDynamicSharedMemorySize, (KC * RPB + 64 * BATCH) * 4);
        inl_mode = (e == hipSuccess) ? 1 : 0;
    }

    if (inl_mode) {
        k_lstm_persist<1><<<NBLK, NTHR, (KC * RPB + 64 * BATCH) * 4, stream>>>(
            x, xT, use_xt, Wt, use_wt, wih0, whh0, wih1, whh1, bias0, bias1,
            h0, c0, out, Gpart, hT, cbuf, barcnt);
    } else {
        k_lstm_persist<0><<<NBLK, NTHR, KC * RPB * 4, stream>>>(
            x, xT, use_xt, Wt, use_wt, wih0, whh0, wih1, whh1, bias0, bias1,
            h0, c0, out, Gpart, hT, cbuf, barcnt);
    }
}

// Round 3
// 50565.518 us; speedup vs baseline: 1.3188x; 1.3188x over previous
//
#include <hip/hip_runtime.h>
#include <cmath>

// ---------------- problem constants ----------------
#define BATCH 64
#define SEQL  512
#define INDIM 512
#define HID   768
#define G4    3072          // 4*HID
#define KTOT  1280          // INDIM + HID
#define KS    10            // K splits (chunk = 128)
#define KC    128
#define JB    24            // row blocks of 128 rows
#define RPB   128
#define NBLK  480           // 2 * JB * KS ; 64KB weight tile each
#define NTHR  256
#define E2    (2*BATCH*HID)
#define HALLN ((size_t)BATCH*SEQL*2*HID)

// ---- agent-scope (cross-XCD coherent, L1/L2-bypassing) accessors; NO fences ----
__device__ __forceinline__ float agld(const float* p) {
    return __hip_atomic_load(p, __ATOMIC_RELAXED, __HIP_MEMORY_SCOPE_AGENT);
}
__device__ __forceinline__ void agst(float* p, float v) {
    __hip_atomic_store(p, v, __ATOMIC_RELAXED, __HIP_MEMORY_SCOPE_AGENT);
}

// ---- fence-free grid barrier: per-wave store drain + relaxed arrive/spin ----
__device__ __forceinline__ void grid_barrier(unsigned* cnt, unsigned target) {
    asm volatile("s_waitcnt vmcnt(0)" ::: "memory");  // drain this wave's sc0sc1 stores
    __syncthreads();                                  // all waves drained
    if (threadIdx.x == 0) {
        __hip_atomic_fetch_add(cnt, 1u, __ATOMIC_RELAXED, __HIP_MEMORY_SCOPE_AGENT);
        while (__hip_atomic_load(cnt, __ATOMIC_RELAXED, __HIP_MEMORY_SCOPE_AGENT) < target)
            __builtin_amdgcn_s_sleep(2);
    }
    __syncthreads();
    asm volatile("" ::: "memory");                    // compiler ordering only
}

__device__ __forceinline__ float sigmoidf_(float x) { return 1.0f / (1.0f + expf(-x)); }

// ---------------- pre-kernel: transpose x -> xT[t][k][b] ----------------
__global__ __launch_bounds__(256) void k_transpose_x(const float* __restrict__ x,
                                                     float* __restrict__ xT) {
    __shared__ float tile[64][65];
    const int t  = blockIdx.x >> 3;
    const int kt = (blockIdx.x & 7) * 64;
    const int tid = threadIdx.x;
#pragma unroll
    for (int p = 0; p < 16; ++p) {
        int idx = p * 256 + tid;
        int b = idx >> 6, kl = idx & 63;
        tile[b][kl] = x[((size_t)b * SEQL + t) * INDIM + kt + kl];
    }
    __syncthreads();
#pragma unroll
    for (int p = 0; p < 16; ++p) {
        int idx = p * 256 + tid;
        int kl = idx >> 6, b = idx & 63;
        xT[((size_t)t * INDIM + kt + kl) * BATCH + b] = tile[b][kl];
    }
}

// ---------------- pre-kernel: pack weights -> Wt[d][k][r] ----------------
__global__ __launch_bounds__(256) void k_pack_w(const float* __restrict__ wih0,
                                                const float* __restrict__ whh0,
                                                const float* __restrict__ wih1,
                                                const float* __restrict__ whh1,
                                                float* __restrict__ Wt) {
    __shared__ float tile[64][65];
    const int d   = blockIdx.x / 960;
    const int rem = blockIdx.x % 960;
    const int kt  = rem / 48;
    const int rt  = rem % 48;
    const float* wih = d ? wih1 : wih0;
    const float* whh = d ? whh1 : whh0;
    const int kbase = kt * 64, rbase = rt * 64;
    const int tid = threadIdx.x;
#pragma unroll
    for (int p = 0; p < 16; ++p) {
        int idx = p * 256 + tid;
        int rl = idx >> 6, kl = idx & 63;
        int k = kbase + kl, r = rbase + rl;
        tile[rl][kl] = (k < INDIM) ? wih[(size_t)r * INDIM + k]
                                   : whh[(size_t)r * HID + (k - INDIM)];
    }
    __syncthreads();
#pragma unroll
    for (int p = 0; p < 16; ++p) {
        int idx = p * 256 + tid;
        int kl = idx >> 6, rl = idx & 63;
        Wt[((size_t)d * KTOT + kbase + kl) * G4 + rbase + rl] = tile[rl][kl];
    }
}

// ---------------- persistent LSTM: weights pinned in LDS ----------------
template <int INL>
__global__ __launch_bounds__(NTHR, 2)
void k_lstm_persist(const float* __restrict__ x,   const float* __restrict__ xT, int use_xt,
                    const float* __restrict__ Wt,  int use_wt,
                    const float* __restrict__ wih0, const float* __restrict__ whh0,
                    const float* __restrict__ wih1, const float* __restrict__ whh1,
                    const float* __restrict__ bias0, const float* __restrict__ bias1,
                    const float* __restrict__ h0,   const float* __restrict__ c0,
                    float* __restrict__ out,  float* __restrict__ Gpart,
                    float* __restrict__ hT,   unsigned* __restrict__ barcnt)
{
    extern __shared__ float smem[];
    float* WL  = smem;                 // [KC][RPB] 64KB
    float* InL = smem + KC * RPB;      // [64][BATCH] 16KB (INL=1)

    const int tid = threadIdx.x;
    const int bid = blockIdx.x;
    const int d   = bid / (JB * KS);
    const int rem = bid % (JB * KS);
    const int rb  = rem / KS;
    const int kb  = rem % KS;
    const int r0  = rb * RPB;
    const int k0  = kb * KC;
    const int tr  = tid & 31;
    const int tb  = tid >> 5;
    const int gtid = bid * NTHR + tid;
    unsigned bar = 0;

    // ---- load this block's 128x128 weight tile into LDS (once) ----
    if (use_wt) {
        const float* wbase = Wt + (size_t)d * KTOT * G4;
#pragma unroll
        for (int p = 0; p < 16; ++p) {
            int idx = p * NTHR + tid;
            int f4 = idx & 31, kl = idx >> 5;
            *(float4*)&WL[kl * RPB + f4 * 4] =
                *(const float4*)(wbase + (size_t)(k0 + kl) * G4 + r0 + f4 * 4);
        }
    } else {
        const float* wih = d ? wih1 : wih0;
        const float* whh = d ? whh1 : whh0;
        for (int p = 0; p < 64; ++p) {
            int idx = p * NTHR + tid;
            int r = idx & 127, kl = idx >> 7;
            int k = k0 + kl;
            WL[kl * RPB + r] = (k < INDIM)
                ? wih[(size_t)(r0 + r) * INDIM + k]
                : whh[(size_t)(r0 + r) * HID + (k - INDIM)];
        }
    }

    // ---- phase-2 ownership: one state element per thread, c kept in register ----
    const int own = (gtid < E2);
    int b2 = 0, dd2 = 0, j2 = 0;
    float c_reg = 0.0f, bias4[4] = {0, 0, 0, 0};
    size_t ci = 0;
    if (own) {
        b2 = gtid / (2 * HID);
        int rr = gtid % (2 * HID);
        dd2 = rr / HID; j2 = rr % HID;
        const float* bs = dd2 ? bias1 : bias0;
        bias4[0] = bs[j2]; bias4[1] = bs[HID + j2];
        bias4[2] = bs[2 * HID + j2]; bias4[3] = bs[3 * HID + j2];
        ci = (size_t)(dd2 * BATCH + b2) * HID + j2;
        c_reg = c0[ci];
        agst(&hT[(size_t)(dd2 * HID + j2) * BATCH + b2], h0[ci]);
    }
    grid_barrier(barcnt, (++bar) * NBLK);

    for (int t = 0; t < SEQL; ++t) {
        const int t_eff = d ? (SEQL - 1 - t) : t;

        // ================= phase 1: partial GEMM =================
        float acc[8][4];
#pragma unroll
        for (int i = 0; i < 8; ++i)
#pragma unroll
            for (int m = 0; m < 4; ++m) acc[i][m] = 0.0f;

#pragma unroll
        for (int c = 0; c < 2; ++c) {
            const int kc0 = k0 + c * 64;

            if (INL) {
                __syncthreads();
                if (kc0 < INDIM) {
                    if (use_xt) {
                        const float* src64 = xT + ((size_t)t_eff * INDIM + kc0) * BATCH;
#pragma unroll
                        for (int p = 0; p < 4; ++p) {
                            int idx = p * NTHR + tid;
                            int b4 = idx & 15, kr = idx >> 4;
                            *(float4*)&InL[kr * BATCH + b4 * 4] =
                                *(const float4*)(src64 + (size_t)kr * BATCH + b4 * 4);
                        }
                    } else {
#pragma unroll
                        for (int p = 0; p < 16; ++p) {
                            int idx = p * NTHR + tid;
                            int b = idx & 63, kr = idx >> 6;
                            InL[kr * BATCH + b] =
                                x[((size_t)b * SEQL + t_eff) * INDIM + kc0 + kr];
                        }
                    }
                } else {
                    const float* hsrc = hT + ((size_t)d * HID + (kc0 - INDIM)) * BATCH;
#pragma unroll
                    for (int p = 0; p < 16; ++p) {
                        int idx = p * NTHR + tid;      // 4096 dwords, coalesced
                        InL[idx] = agld(hsrc + idx);
                    }
                }
                __syncthreads();
#pragma unroll 8
                for (int k = 0; k < 64; ++k) {
                    float4 w = *(const float4*)&WL[(c * 64 + k) * RPB + tr * 4];
                    float4 a0 = *(const float4*)&InL[k * BATCH + tb * 8];
                    float4 a1 = *(const float4*)&InL[k * BATCH + tb * 8 + 4];
                    float av[8] = {a0.x, a0.y, a0.z, a0.w, a1.x, a1.y, a1.z, a1.w};
                    float wv[4] = {w.x, w.y, w.z, w.w};
#pragma unroll
                    for (int bi = 0; bi < 8; ++bi)
#pragma unroll
                        for (int m = 0; m < 4; ++m)
                            acc[bi][m] = fmaf(av[bi], wv[m], acc[bi][m]);
                }
            } else {
                // 64KB fallback: operands straight from global
#pragma unroll 4
                for (int k = 0; k < 64; ++k) {
                    float4 w = *(const float4*)&WL[(c * 64 + k) * RPB + tr * 4];
                    float av[8];
                    if (kc0 < INDIM && use_xt) {
                        const float* src64 = xT + ((size_t)t_eff * INDIM + kc0) * BATCH;
                        float4 a0 = *(const float4*)(src64 + (size_t)k * BATCH + tb * 8);
                        float4 a1 = *(const float4*)(src64 + (size_t)k * BATCH + tb * 8 + 4);
                        av[0]=a0.x; av[1]=a0.y; av[2]=a0.z; av[3]=a0.w;
                        av[4]=a1.x; av[5]=a1.y; av[6]=a1.z; av[7]=a1.w;
                    } else if (kc0 < INDIM) {
#pragma unroll
                        for (int bi = 0; bi < 8; ++bi)
                            av[bi] = x[((size_t)(tb * 8 + bi) * SEQL + t_eff) * INDIM + kc0 + k];
                    } else {
                        const float* hsrc = hT + ((size_t)d * HID + (kc0 - INDIM)) * BATCH;
#pragma unroll
                        for (int bi = 0; bi < 8; ++bi)
                            av[bi] = agld(hsrc + (size_t)k * BATCH + tb * 8 + bi);
                    }
                    float wv[4] = {w.x, w.y, w.z, w.w};
#pragma unroll
                    for (int bi = 0; bi < 8; ++bi)
#pragma unroll
                        for (int m = 0; m < 4; ++m)
                            acc[bi][m] = fmaf(av[bi], wv[m], acc[bi][m]);
                }
            }
        }
        // ---- write partials via agent-scope stores (LLC-coherent, no fence) ----
        {
            float* gp = Gpart + (size_t)(d * KS + kb) * ((size_t)BATCH * G4) + r0;
#pragma unroll
            for (int bi = 0; bi < 8; ++bi) {
                float* row = gp + (size_t)(tb * 8 + bi) * G4 + tr * 4;
#pragma unroll
                for (int m = 0; m < 4; ++m) agst(row + m, acc[bi][m]);
            }
        }
        grid_barrier(barcnt, (++bar) * NBLK);

        // ================= phase 2: reduce + activations + state =================
        if (own) {
            const size_t slice = (size_t)BATCH * G4;
            const float* gbase = Gpart + (size_t)dd2 * KS * slice + (size_t)b2 * G4 + j2;
            float gv0 = bias4[0], gv1 = bias4[1], gv2 = bias4[2], gv3 = bias4[3];
#pragma unroll
            for (int q = 0; q < KS; ++q) {
                const float* gp = gbase + (size_t)q * slice;
                gv0 += agld(gp);
                gv1 += agld(gp + HID);
                gv2 += agld(gp + 2 * HID);
                gv3 += agld(gp + 3 * HID);
            }
            float ig = sigmoidf_(gv0);
            float fg = sigmoidf_(gv1);
            float gg = tanhf(gv2);
            float og = sigmoidf_(gv3);
            c_reg = fg * c_reg + ig * gg;
            float hn = og * tanhf(c_reg);
            agst(&hT[(size_t)(dd2 * HID + j2) * BATCH + b2], hn);
            int t_out = dd2 ? (SEQL - 1 - t) : t;
            __builtin_nontemporal_store(hn,
                &out[((size_t)b2 * SEQL + t_out) * (2 * HID) + dd2 * HID + j2]);
            if (t == SEQL - 1) {
                out[HALLN + ci] = hn;
                out[HALLN + E2 + ci] = c_reg;
            }
        }
        grid_barrier(barcnt, (++bar) * NBLK);
    }
}

// ---------------- launcher ----------------
extern "C" void kernel_launch(void* const* d_in, const int* in_sizes, int n_in,
                              void* d_out, int out_size, void* d_ws, size_t ws_size,
                              hipStream_t stream) {
    const float* x     = (const float*)d_in[0];
    const float* wih0  = (const float*)d_in[1];
    const float* whh0  = (const float*)d_in[2];
    const float* bias0 = (const float*)d_in[3];
    const float* wih1  = (const float*)d_in[4];
    const float* whh1  = (const float*)d_in[5];
    const float* bias1 = (const float*)d_in[6];
    const float* h0    = (const float*)d_in[7];
    const float* c0    = (const float*)d_in[8];
    float* out = (float*)d_out;
    float* ws  = (float*)d_ws;

    size_t off = 0;
    float* Gpart = ws + off; off += (size_t)2 * KS * BATCH * G4;
    float* hT    = ws + off; off += (size_t)2 * HID * BATCH;
    off += (size_t)2 * BATCH * HID;            // (hole; keeps layout stable)
    unsigned* barcnt = (unsigned*)(ws + off); off += 64;
    float* Wt = ws + off;
    size_t off_wt = off + (size_t)2 * KTOT * G4;
    float* xT = ws + off_wt;
    size_t off_xt = off_wt + (size_t)SEQL * INDIM * BATCH;
    int use_wt = (ws_size >= off_wt * sizeof(float)) ? 1 : 0;
    int use_xt = (ws_size >= off_xt * sizeof(float)) ? 1 : 0;

    hipMemsetAsync(barcnt, 0, 256, stream);
    if (use_wt) k_pack_w<<<1920, 256, 0, stream>>>(wih0, whh0, wih1, whh1, Wt);
    if (use_xt) k_transpose_x<<<4096, 256, 0, stream>>>(x, xT);

    // 80KB dynamic LDS opt-in (host-side attr set; same decision every call)
    hipError_t e = hipFuncSetAttribute(
        reinterpret_cast<const void*>(&k_lstm_persist<1>),
        hipFuncAttributeMaxDynamicSharedMemorySize, (KC * RPB + 64 * BATCH) * 4);

    if (e == hipSuccess) {
        k_lstm_persist<1><<<NBLK, NTHR, (KC * RPB + 64 * BATCH) * 4, stream>>>(
            x, xT, use_xt, Wt, use_wt, wih0, whh0, wih1, whh1, bias0, bias1,
            h0, c0, out, Gpart, hT, barcnt);
    } else {
        k_lstm_persist<0><<<NBLK, NTHR, KC * RPB * 4, stream>>>(
            x, xT, use_xt, Wt, use_wt, wih0, whh0, wih1, whh1, bias0, bias1,
            h0, c0, out, Gpart, hT, barcnt);
    }
}